// Round 7
// baseline (988.396 us; speedup 1.0000x reference)
//
#include <hip/hip_runtime.h>

// QuantMatMul: fake-quant(A) @ fake-quant(B), computed exactly via i8 MFMA.
// A: [4,4096,4096] fp32 -> folded to M=16384 rows. B: [4096,4096] fp32 (K x N).
// C = s_a*s_b * ( A'B' - zb*rowsumA[m] - za*colsumB[n] + K*za*zb ),  A',B' in i8.
//
// Round 9: B operand DIRECT from L2/LLC (Bt is 16MB, LLC-resident) into
// registers -- no B staging, no B LDS reads. LDS/half drops 128KB->80KB
// (1143->714 cyc vs matrix 1171); barriers 4->2 per half. A stays LDS-staged
// (4 x 16KiB slots, pre-swizzled source, 0 conflicts). Two counted waits per
// half: W1=vmcnt(4) (B-k0 frags ready), W2=vmcnt(4) (B-k1 ready); issue order
// pinned by asm volatile + sched_barrier so counts are exact. Single-buffered
// B regs (16 VGPR), loads issued right after the consuming MFMA cluster.
// Tail (init/minmax/prep2) unchanged from R8 -- measured structure-insensitive.

#define K_DIM 4096
#define N_COLS 4096
#define M_ROWS 16384

typedef __attribute__((ext_vector_type(4))) int int4v;
typedef __attribute__((ext_vector_type(16))) int int16v;

// ---- workspace layout ----
static const size_t OFF_AQ = 0;                                  // 64 MiB  i8 [16384][4096] (plain)
static const size_t OFF_BT = (size_t)64 << 20;                   // 16 MiB  i8 [4096][4096] (B^T, plain)
static const size_t OFF_RS = OFF_BT + ((size_t)16 << 20);        // 64 KiB  int rowsumA
static const size_t OFF_CS = OFF_RS + (size_t)M_ROWS * 4;        // 16 KiB  int colsumB
static const size_t OFF_MM = OFF_CS + (size_t)N_COLS * 4;        // 64 B    minmax enc

// sortable encoding for float atomic min/max
__device__ __forceinline__ unsigned enc_f(float f) {
  unsigned u = __float_as_uint(f);
  return (u & 0x80000000u) ? ~u : (u | 0x80000000u);
}
__device__ __forceinline__ float dec_f(unsigned e) {
  unsigned u = (e & 0x80000000u) ? (e & 0x7fffffffu) : ~e;
  return __uint_as_float(u);
}

// reciprocal-multiply quantize: matches ref's clip(rint(x/s)+zp,0,255), -128 shift
__device__ __forceinline__ int quantize1(float x, float r, float zp) {
  return (int)(fminf(fmaxf(rintf(x * r) + zp, 0.0f), 255.0f)) - 128;
}

__device__ __forceinline__ void gload16(const void* g, void* l) {
  __builtin_amdgcn_global_load_lds(
      (const __attribute__((address_space(1))) unsigned int*)g,
      (__attribute__((address_space(3))) unsigned int*)l, 16, 0, 0);
}

__device__ __forceinline__ void qparams_a(const unsigned* mm, float& ra, float& zpa) {
  const float amin = dec_f(mm[0]), amax = dec_f(mm[1]);
  const float sa = fmaxf((amax - amin) / 255.0f, 1e-8f);
  zpa = rintf(-amin / sa);
  ra = 1.0f / sa;
}
__device__ __forceinline__ void qparams_b(const unsigned* mm, float& rb, float& zpb) {
  const float bmin = dec_f(mm[2]), bmax = dec_f(mm[3]);
  const float sb = fmaxf((bmax - bmin) / 255.0f, 1e-8f);
  zpb = rintf(-bmin / sb);
  rb = 1.0f / sb;
}

// init: minmax sentinels + zero colsum (prep2 accumulates into it atomically)
__global__ __launch_bounds__(256) void init_k(unsigned* __restrict__ mm,
                                              int* __restrict__ colsum) {
  const int i = blockIdx.x * 256 + threadIdx.x;
  if (i < N_COLS) colsum[i] = 0;
  if (i == N_COLS) {
    mm[0] = 0xFFFFFFFFu; mm[1] = 0u;   // A min/max (encoded)
    mm[2] = 0xFFFFFFFFu; mm[3] = 0u;   // B min/max
  }
}

// fused minmax over A (blocks 0..4095) and B (blocks 4096..5119)
__global__ __launch_bounds__(256) void minmax_k(const float4* __restrict__ A,
                                                const float4* __restrict__ B,
                                                unsigned* __restrict__ mm) {
  const bool isB = blockIdx.x >= 4096;
  const float4* __restrict__ x = isB ? B : A;
  const int bid = isB ? (int)blockIdx.x - 4096 : (int)blockIdx.x;
  unsigned* m = mm + (isB ? 2 : 0);
  const int t = threadIdx.x;
  const long i0 = (long)bid * 256 + t;
  const long STR = isB ? (long)1024 * 256 : (long)4096 * 256;

  float lo = 3.402823466e38f, hi = -3.402823466e38f;
#pragma unroll
  for (int g = 0; g < 4; ++g) {
    float4 v0 = x[i0 + (long)(4 * g + 0) * STR];
    float4 v1 = x[i0 + (long)(4 * g + 1) * STR];
    float4 v2 = x[i0 + (long)(4 * g + 2) * STR];
    float4 v3 = x[i0 + (long)(4 * g + 3) * STR];
    lo = fminf(lo, fminf(fminf(v0.x, v0.y), fminf(v0.z, v0.w)));
    hi = fmaxf(hi, fmaxf(fmaxf(v0.x, v0.y), fmaxf(v0.z, v0.w)));
    lo = fminf(lo, fminf(fminf(v1.x, v1.y), fminf(v1.z, v1.w)));
    hi = fmaxf(hi, fmaxf(fmaxf(v1.x, v1.y), fmaxf(v1.z, v1.w)));
    lo = fminf(lo, fminf(fminf(v2.x, v2.y), fminf(v2.z, v2.w)));
    hi = fmaxf(hi, fmaxf(fmaxf(v2.x, v2.y), fmaxf(v2.z, v2.w)));
    lo = fminf(lo, fminf(fminf(v3.x, v3.y), fminf(v3.z, v3.w)));
    hi = fmaxf(hi, fmaxf(fmaxf(v3.x, v3.y), fmaxf(v3.z, v3.w)));
  }
  for (int off = 32; off; off >>= 1) {
    lo = fminf(lo, __shfl_down(lo, off));
    hi = fmaxf(hi, __shfl_down(hi, off));
  }
  __shared__ float slo[4], shi[4];
  if ((t & 63) == 0) { slo[t >> 6] = lo; shi[t >> 6] = hi; }
  __syncthreads();
  if (t == 0) {
    for (int w = 1; w < 4; w++) { lo = fminf(lo, slo[w]); hi = fmaxf(hi, shi[w]); }
    atomicMin(&m[0], enc_f(lo));
    atomicMax(&m[1], enc_f(hi));
  }
}

// fused quant pass:
//   blocks 0..2047    : quantize 8 rows of A each (plain layout) + rowsum
//   blocks 2048..2559 : quantize+transpose 8 64x64 tiles of B each + colsum
__global__ __launch_bounds__(256) void prep2_k(const float* __restrict__ A,
                                               const float* __restrict__ B,
                                               signed char* __restrict__ Aq,
                                               signed char* __restrict__ Bt,
                                               int* __restrict__ rowsum,
                                               int* __restrict__ colsum,
                                               const unsigned* __restrict__ mm) {
  __shared__ unsigned char s[64][72];
  __shared__ int sw[4];
  const int t = threadIdx.x;
  const int bid = blockIdx.x;

  if (bid < 2048) {
    float ra, zpa;
    qparams_a(mm, ra, zpa);
#pragma unroll 1
    for (int rr = 0; rr < 8; ++rr) {
      const int row = bid * 8 + rr;
      const float4* src = (const float4*)(A + (size_t)row * K_DIM);
      unsigned* dst = (unsigned*)(Aq + (size_t)row * K_DIM);
      int sum = 0;
#pragma unroll
      for (int j = 0; j < 4; j++) {
        const int d = j * 256 + t;       // dword index in row (0..1023)
        float4 v = src[d];
        int q0 = quantize1(v.x, ra, zpa);
        int q1 = quantize1(v.y, ra, zpa);
        int q2 = quantize1(v.z, ra, zpa);
        int q3 = quantize1(v.w, ra, zpa);
        sum += q0 + q1 + q2 + q3;
        dst[d] = ((unsigned)q0 & 255u) | (((unsigned)q1 & 255u) << 8) |
                 (((unsigned)q2 & 255u) << 16) | (((unsigned)q3 & 255u) << 24);
      }
      for (int off = 32; off; off >>= 1) sum += __shfl_down(sum, off);
      if ((t & 63) == 0) sw[t >> 6] = sum;
      __syncthreads();
      if (t == 0) rowsum[row] = sw[0] + sw[1] + sw[2] + sw[3];
      __syncthreads();                   // protect sw reuse next row
    }
  } else {
    float rb, zpb;
    qparams_b(mm, rb, zpb);
    const int kr = t >> 2, tl = t & 3;
    const int nr = t >> 2, kb = tl * 16;
#pragma unroll 1
    for (int j8 = 0; j8 < 8; ++j8) {
      const int ti = (bid - 2048) * 8 + j8;     // 0..4095
      const int n0 = (ti & 63) * 64, k0 = (ti >> 6) * 64;
      const float* rowp = B + (size_t)(k0 + kr) * N_COLS + n0;
#pragma unroll
      for (int j = 0; j < 4; j++) {
        const int fi = tl + j * 4;
        float4 v = *(const float4*)(rowp + fi * 4);
        int q0 = quantize1(v.x, rb, zpb);
        int q1 = quantize1(v.y, rb, zpb);
        int q2 = quantize1(v.z, rb, zpb);
        int q3 = quantize1(v.w, rb, zpb);
        *(unsigned*)&s[kr][fi * 4] = ((unsigned)q0 & 255u) | (((unsigned)q1 & 255u) << 8) |
                                     (((unsigned)q2 & 255u) << 16) | (((unsigned)q3 & 255u) << 24);
      }
      __syncthreads();
      unsigned w[4];
      int psum = 0;
#pragma unroll
      for (int jj = 0; jj < 4; jj++) {
        unsigned b0 = s[kb + jj * 4 + 0][nr];
        unsigned b1 = s[kb + jj * 4 + 1][nr];
        unsigned b2 = s[kb + jj * 4 + 2][nr];
        unsigned b3 = s[kb + jj * 4 + 3][nr];
        w[jj] = b0 | (b1 << 8) | (b2 << 16) | (b3 << 24);
        psum += (int)(signed char)b0 + (int)(signed char)b1 +
                (int)(signed char)b2 + (int)(signed char)b3;
      }
      int4v o = {(int)w[0], (int)w[1], (int)w[2], (int)w[3]};
      *(int4v*)(Bt + (size_t)(n0 + nr) * K_DIM + (k0 + kb)) = o;
      psum += __shfl_xor(psum, 1);
      psum += __shfl_xor(psum, 2);
      if (tl == 0) atomicAdd(&colsum[n0 + nr], psum);
      __syncthreads();                   // protect s reuse next tile
    }
  }
}

// ---- i8 GEMM: 256x256 tile, 8 waves (2M x 4N), wave = 128x64 ----
// A in LDS (4 x 16KiB half-slots, 64 pseudo-rows x 256B, block g at g^(R&7));
// B direct from cache into regs: lane reads Bt[n0+wn+32ni+r32][64H+32kk+16h].
__global__ __launch_bounds__(512, 2) void gemm_k(const signed char* __restrict__ Aq,
                                                 const signed char* __restrict__ Bt,
                                                 float* __restrict__ C,
                                                 const int* __restrict__ rowsum,
                                                 const int* __restrict__ colsum,
                                                 const unsigned* __restrict__ mm) {
  __shared__ signed char lds[65536];   // 4 half-slots x 16 KiB (A only)
  const int t = threadIdx.x;

  // XCD-bijective swizzle: 1024 wgs, 8 XCDs, 128/XCD (8m x 16n chunk)
  const int orig = blockIdx.x;
  const int wgid = (orig & 7) * 128 + (orig >> 3);
  const int m0 = (wgid >> 4) * 256;
  const int n0 = (wgid & 15) * 256;

  const int w = t >> 6, l = t & 63;
  const int wm4 = (w >> 2) * 32;        // (wave m-offset)/4 : 2M waves of 128 rows
  const int wn = (w & 3) * 64;          // wave n-offset : 4N waves of 64 cols
  const int r32 = l & 31, h = l >> 5;
  const int u = r32 >> 2, c4 = (r32 & 3) * 4;

  // tile-invariant A LDS read addresses (half-slot-relative)
  unsigned aAddr[4][2];
#pragma unroll
  for (int mi = 0; mi < 4; ++mi)
#pragma unroll
    for (int kk = 0; kk < 2; ++kk)
      aAddr[mi][kk] = (unsigned)(wm4 + 8 * mi + u) * 256 +
                      ((unsigned)((c4 + 2 * kk + h) ^ u) << 4);

  // A staging: per-lane pre-swizzled global source, lane-linear LDS dest.
  const int bs_ = t & 15, Rq = t >> 4;
  const int b16 = bs_ ^ (Rq & 7);
  const int sc = b16 >> 2, slb = b16 & 3;
  const signed char* pA0 = Aq + (size_t)(m0 + 4 * Rq + sc) * K_DIM + slb * 16;
  const signed char* pA1 = pA0 + (size_t)128 * K_DIM;

  // B direct per-lane pointers (half 0); ni=0 -> pBf0, ni=1 -> pBf1
  const signed char* pBf0 = Bt + (size_t)(n0 + wn + r32) * K_DIM + h * 16;
  const signed char* pBf1 = pBf0 + (size_t)32 * K_DIM;

  int16v acc[4][2] = {};
  int4v a0, a1, a2, a3;
  int4v b0, b1, b2, b3;   // B frags for current half: (ni,kk)=(0,0),(1,0),(0,1),(1,1)

#define STAGE_A(SN) do {                                  \
    gload16(pA0, lds + (SN) + t * 16);                    \
    gload16(pA1, lds + (SN) + 8192 + t * 16);             \
    pA0 += 64; pA1 += 64; } while (0)

#define LOADB(DST, PTR, OFF)                                         \
    asm volatile("global_load_dwordx4 %0, %1, off offset:" #OFF      \
                 : "=v"(DST) : "v"(PTR))

#define MM_(A, B, CC) CC = __builtin_amdgcn_mfma_i32_32x32x32_i8(A, B, CC, 0, 0, 0)

#define RDA(SC, KK)                                                  \
    a0 = *(const int4v*)(lds + (SC) + aAddr[0][KK]);                 \
    a1 = *(const int4v*)(lds + (SC) + aAddr[1][KK]);                 \
    a2 = *(const int4v*)(lds + (SC) + aAddr[2][KK]);                 \
    a3 = *(const int4v*)(lds + (SC) + aAddr[3][KK]);

#define MFMA8(B0, B1)                                                \
    __builtin_amdgcn_s_setprio(1);                                   \
    MM_(a0, B0, acc[0][0]); MM_(a0, B1, acc[0][1]);                  \
    MM_(a1, B0, acc[1][0]); MM_(a1, B1, acc[1][1]);                  \
    MM_(a2, B0, acc[2][0]); MM_(a2, B1, acc[2][1]);                  \
    MM_(a3, B0, acc[3][0]); MM_(a3, B1, acc[3][1]);                  \
    __builtin_amdgcn_s_setprio(0);

#define WAITN(N) asm volatile("s_waitcnt vmcnt(" #N ")" ::: "memory")
#define SCHED0 __builtin_amdgcn_sched_barrier(0)
#define SBAR do { SCHED0; __builtin_amdgcn_s_barrier(); SCHED0; } while (0)

  // Half H: W1 vmcnt -> barrier -> RDA(k0) -> MFMA8(b0,b1) -> issue B01(H+1)
  //         -> RDA(k1) -> W2 vmcnt -> MFMA8(b2,b3) -> issue B23(H+1)
  //         -> [stage A(H+3)] -> barrier.
  // vmcnt counts (2 loads per group, FIFO): W1 needs B01(H) -> younger
  // {B23(H), S(H+2)} = 4; W2 needs B23(H) -> younger {S(H+2), B01(H+1)} = 4.
#define HALF_F(SC, SN) do {                                          \
    WAITN(4); SBAR;                                                  \
    RDA(SC, 0)                                                       \
    MFMA8(b0, b1)                                                    \
    LOADB(b0, pBf0, 0); LOADB(b1, pBf1, 0);                          \
    RDA(SC, 1)                                                       \
    WAITN(4); SCHED0;                                                \
    MFMA8(b2, b3)                                                    \
    LOADB(b2, pBf0, 32); LOADB(b3, pBf1, 32);                        \
    pBf0 += 64; pBf1 += 64;                                          \
    SCHED0; STAGE_A(SN);                                             \
    SBAR;                                                            \
  } while (0)
#define HALF_B(SC, W1N, W2N) do {                                    \
    WAITN(W1N); SBAR;                                                \
    RDA(SC, 0)                                                       \
    MFMA8(b0, b1)                                                    \
    LOADB(b0, pBf0, 0); LOADB(b1, pBf1, 0);                          \
    RDA(SC, 1)                                                       \
    WAITN(W2N); SCHED0;                                              \
    MFMA8(b2, b3)                                                    \
    LOADB(b2, pBf0, 32); LOADB(b3, pBf1, 32);                        \
    pBf0 += 64; pBf1 += 64;                                          \
    SBAR;                                                            \
  } while (0)
#define HALF_L(SC) do {                                              \
    WAITN(2); SBAR;                                                  \
    RDA(SC, 0)                                                       \
    MFMA8(b0, b1)                                                    \
    RDA(SC, 1)                                                       \
    WAITN(0); SCHED0;                                                \
    MFMA8(b2, b3)                                                    \
  } while (0)

  // prologue: S_0, S_1, B01_0, B23_0, S_2 (order pinned for W1(0)=vmcnt(4))
  STAGE_A(0); STAGE_A(16384);
  SCHED0;
  LOADB(b0, pBf0, 0);  LOADB(b1, pBf1, 0);
  LOADB(b2, pBf0, 32); LOADB(b3, pBf1, 32);
  pBf0 += 64; pBf1 += 64;
  SCHED0;
  STAGE_A(32768);

#pragma unroll 1
  for (int g = 0; g < 15; ++g) {       // halves 0..59
    HALF_F(0, 49152);
    HALF_F(16384, 0);
    HALF_F(32768, 16384);
    HALF_F(49152, 32768);
  }
  HALF_F(0, 49152);                    // H=60 (stages S_63)
  HALF_B(16384, 4, 4);                 // H=61 (loads B_62)
  HALF_B(32768, 2, 2);                 // H=62 (loads B_63)
  HALF_L(49152);                       // H=63

#undef STAGE_A
#undef LOADB
#undef MM_
#undef RDA
#undef MFMA8
#undef WAITN
#undef SCHED0
#undef SBAR
#undef HALF_F
#undef HALF_B
#undef HALF_L

  // epilogue: integer zero-point corrections (exact), then scale.
  // C/D layout (32x32): col = lane&31, row = (reg&3) + 8*(reg>>2) + 4*(lane>>5)
  const float amin = dec_f(mm[0]), amax = dec_f(mm[1]);
  const float bmin = dec_f(mm[2]), bmax = dec_f(mm[3]);
  const float sa = fmaxf((amax - amin) / 255.0f, 1e-8f);
  const float sb = fmaxf((bmax - bmin) / 255.0f, 1e-8f);
  const int za = (int)rintf(-amin / sa) - 128;
  const int zb = (int)rintf(-bmin / sb) - 128;
  const float sab = sa * sb;
  const int kzz = K_DIM * za * zb;
  const int wm = wm4 * 4;
  const int col0 = n0 + wn + r32;
  const int cs0 = za * colsum[col0];
  const int cs1 = za * colsum[col0 + 32];
#pragma unroll
  for (int mi = 0; mi < 4; ++mi) {
    const int rbase = m0 + wm + mi * 32 + 4 * h;
#pragma unroll
    for (int r = 0; r < 16; ++r) {
      const int row = rbase + (r & 3) + 8 * (r >> 2);
      const int base = kzz - zb * rowsum[row];
      C[(size_t)row * N_COLS + col0]      = sab * (float)(acc[mi][0][r] + base - cs0);
      C[(size_t)row * N_COLS + col0 + 32] = sab * (float)(acc[mi][1][r] + base - cs1);
    }
  }
}

extern "C" void kernel_launch(void* const* d_in, const int* in_sizes, int n_in,
                              void* d_out, int out_size, void* d_ws, size_t ws_size,
                              hipStream_t stream) {
  const float* A = (const float*)d_in[0];
  const float* B = (const float*)d_in[1];
  float* C = (float*)d_out;
  char* ws = (char*)d_ws;
  signed char* Aq = (signed char*)(ws + OFF_AQ);
  signed char* Bt = (signed char*)(ws + OFF_BT);
  int* rowsum = (int*)(ws + OFF_RS);
  int* colsum = (int*)(ws + OFF_CS);
  unsigned* mm = (unsigned*)(ws + OFF_MM);

  init_k<<<17, 256, 0, stream>>>(mm, colsum);
  minmax_k<<<5120, 256, 0, stream>>>((const float4*)A, (const float4*)B, mm);
  prep2_k<<<2560, 256, 0, stream>>>(A, B, Aq, Bt, rowsum, colsum, mm);
  gemm_k<<<1024, 512, 0, stream>>>(Aq, Bt, C, rowsum, colsum, mm);
}